// Round 5
// baseline (13682.227 us; speedup 1.0000x reference)
//
#include <hip/hip_runtime.h>
#include <stdint.h>

#define T_STEPS 1024
#define NGROUP 64               // workgroups per layer
#define NWG 192
#define THREADS 256
#define S_TOTAL (T_STEPS + 2)   // 3-layer pipeline skew
#define HSLICE (64 * 512)       // one timestep of h, elements
#define RING 4                  // h0/h1 ring slots (lockstep -> safe)

typedef __attribute__((ext_vector_type(8))) short bf16x8;
typedef __attribute__((ext_vector_type(4))) float f32x4;
typedef unsigned int uint;
typedef unsigned short ushort;

// ---- helpers -------------------------------------------------------------

__device__ __forceinline__ ushort f2bf(float f) {  // RNE float->bf16
    uint u = __builtin_bit_cast(uint, f);
    u = (u + 0x7FFFu + ((u >> 16) & 1u)) >> 16;
    return (ushort)u;
}

__device__ __forceinline__ float sigm(float x) {
    x = fminf(fmaxf(x, -30.f), 30.f);
    return 1.f / (1.f + __expf(-x));
}

__device__ __forceinline__ float tanh_(float x) {
    x = fminf(fmaxf(x, -15.f), 15.f);
    float e = __expf(2.f * x);
    return (e - 1.f) / (e + 1.f);
}

// 8 consecutive f32 -> bf16x8 fragment
__device__ __forceinline__ bf16x8 packW(const float* __restrict__ p) {
    float4 a = *(const float4*)p, b = *(const float4*)(p + 4);
    bf16x8 r;
    r[0] = (short)f2bf(a.x); r[1] = (short)f2bf(a.y);
    r[2] = (short)f2bf(a.z); r[3] = (short)f2bf(a.w);
    r[4] = (short)f2bf(b.x); r[5] = (short)f2bf(b.y);
    r[6] = (short)f2bf(b.z); r[7] = (short)f2bf(b.w);
    return r;
}

// swizzle for out_gemm's B tile only
__device__ __forceinline__ int swzE(int row, int k) {
    return row * 512 + (k ^ ((row & 7) << 3));
}

// ---- persistent 3-layer pipelined scan ----------------------------------
// Per block: 32 gate-cols (j = wg*8 + 0..7, all 4 gates), weights entirely
// in VGPRs (256 regs), cell state in VGPRs, zero LDS in the loop.
// Barrier: per-block release flag store + all-blocks parallel flag poll.

__global__ __launch_bounds__(THREADS, 1)
void lstm_scan(const float* __restrict__ feat,
               const float* __restrict__ wih0, const float* __restrict__ whh0,
               const float* __restrict__ bih0, const float* __restrict__ bhh0,
               const float* __restrict__ wih1, const float* __restrict__ whh1,
               const float* __restrict__ bih1, const float* __restrict__ bhh1,
               const float* __restrict__ wih2, const float* __restrict__ whh2,
               const float* __restrict__ bih2, const float* __restrict__ bhh2,
               ushort* h0buf, ushort* h1buf, ushort* h2ring, ushort* ybuf,
               uint* flags) {
    const int blk = blockIdx.x, L = blk >> 6, wg = blk & 63;
    const int tid = threadIdx.x, wv = tid >> 6, l = tid & 63;
    const int c16 = l & 15, hi8 = c16 >> 3, jl = c16 & 7, kq = l >> 4;
    const int krow = kq * 8;
    const int rowbase = wv * 16;        // D rows rowbase + kq*4 + r
    const int arow = rowbase + c16;     // A-fragment row (batch)

    const float* wih_g = (L == 0) ? wih0 : (L == 1) ? wih1 : wih2;
    const float* whh_g = (L == 0) ? whh0 : (L == 1) ? whh1 : whh2;
    const float* bih_g = (L == 0) ? bih0 : (L == 1) ? bih1 : bih2;
    const float* bhh_g = (L == 0) ? bhh0 : (L == 1) ? bhh1 : bhh2;
    const ushort* xsrc = (L == 1) ? h0buf : (L == 2) ? h1buf : nullptr;
    ushort* hout = (L == 0) ? h0buf : (L == 1) ? h1buf : nullptr;  // L2: ring

    // col-tile 0 -> gate hi8 (i/f), col-tile 1 -> gate 2+hi8 (g/o)
    const int gcol0 = hi8 * 512 + wg * 8 + jl;
    const int gcol1 = (2 + hi8) * 512 + wg * 8 + jl;

    // ---- weights -> registers (one-time) ----
    bf16x8 whhF[16][2];
    #pragma unroll
    for (int ks = 0; ks < 16; ++ks) {
        whhF[ks][0] = packW(whh_g + (size_t)gcol0 * 512 + ks * 32 + krow);
        whhF[ks][1] = packW(whh_g + (size_t)gcol1 * 512 + ks * 32 + krow);
    }
    bf16x8 wihF[16][2];
    if (L > 0) {
        #pragma unroll
        for (int ks = 0; ks < 16; ++ks) {
            wihF[ks][0] = packW(wih_g + (size_t)gcol0 * 512 + ks * 32 + krow);
            wihF[ks][1] = packW(wih_g + (size_t)gcol1 * 512 + ks * 32 + krow);
        }
    }
    const float bias0 = bih_g[gcol0] + bhh_g[gcol0];
    const float bias1 = bih_g[gcol1] + bhh_g[gcol1];
    float w0a[6], w0b[6];
    if (L == 0) {
        #pragma unroll
        for (int d = 0; d < 6; ++d) {
            w0a[d] = wih0[gcol0 * 6 + d];
            w0b[d] = wih0[gcol1 * 6 + d];
        }
    }
    f32x4 cstv = {0.f, 0.f, 0.f, 0.f};   // cell state, lo lanes own (4 b, j)

    for (int s = 0; s < S_TOTAL; ++s) {
        const int t = s - L;

        // feat prefetch: input-only, independent of barrier -> issue early
        float xv[4][6];
        if (L == 0 && t >= 0 && t < T_STEPS) {
            #pragma unroll
            for (int r = 0; r < 4; ++r)
                #pragma unroll
                for (int d = 0; d < 6; ++d)
                    xv[r][d] = feat[(size_t)((rowbase + kq * 4 + r) * 6 + d) * T_STEPS + t];
        }

        // ---- flag-array barrier: wait for all blocks to finish step s-1 ----
        if (s > 0) {
            for (;;) {
                int ok = 1;
                if (tid < NWG)
                    ok = (__hip_atomic_load(flags + tid * 32, __ATOMIC_RELAXED,
                                            __HIP_MEMORY_SCOPE_AGENT) >= (uint)s);
                if (__syncthreads_and(ok)) break;
                __builtin_amdgcn_s_sleep(2);
            }
            if (tid == 0)
                (void)__hip_atomic_load(flags, __ATOMIC_ACQUIRE,
                                        __HIP_MEMORY_SCOPE_AGENT);
            __syncthreads();
        }

        if (t >= 0 && t < T_STEPS) {
            f32x4 acc0 = {0.f, 0.f, 0.f, 0.f};
            f32x4 acc1 = {0.f, 0.f, 0.f, 0.f};

            if (L > 0) {
                const ushort* xs = xsrc + (size_t)(t & (RING - 1)) * HSLICE
                                   + arow * 512 + krow;
                if (t > 0) {
                    const ushort* hsrc = (L == 2)
                        ? h2ring + (size_t)((t - 1) & 1) * HSLICE
                        : hout + (size_t)((t - 1) & (RING - 1)) * HSLICE;
                    const ushort* hp = hsrc + arow * 512 + krow;
                    bf16x8 ax[16], ah[16];
                    #pragma unroll
                    for (int ks = 0; ks < 16; ++ks) ax[ks] = *(const bf16x8*)(xs + ks * 32);
                    #pragma unroll
                    for (int ks = 0; ks < 16; ++ks) ah[ks] = *(const bf16x8*)(hp + ks * 32);
                    #pragma unroll
                    for (int ks = 0; ks < 16; ++ks) {
                        acc0 = __builtin_amdgcn_mfma_f32_16x16x32_bf16(ax[ks], wihF[ks][0], acc0, 0, 0, 0);
                        acc1 = __builtin_amdgcn_mfma_f32_16x16x32_bf16(ax[ks], wihF[ks][1], acc1, 0, 0, 0);
                        acc0 = __builtin_amdgcn_mfma_f32_16x16x32_bf16(ah[ks], whhF[ks][0], acc0, 0, 0, 0);
                        acc1 = __builtin_amdgcn_mfma_f32_16x16x32_bf16(ah[ks], whhF[ks][1], acc1, 0, 0, 0);
                    }
                } else {
                    bf16x8 ax[16];
                    #pragma unroll
                    for (int ks = 0; ks < 16; ++ks) ax[ks] = *(const bf16x8*)(xs + ks * 32);
                    #pragma unroll
                    for (int ks = 0; ks < 16; ++ks) {
                        acc0 = __builtin_amdgcn_mfma_f32_16x16x32_bf16(ax[ks], wihF[ks][0], acc0, 0, 0, 0);
                        acc1 = __builtin_amdgcn_mfma_f32_16x16x32_bf16(ax[ks], wihF[ks][1], acc1, 0, 0, 0);
                    }
                }
            } else if (t > 0) {
                const ushort* hp = h0buf + (size_t)((t - 1) & (RING - 1)) * HSLICE
                                   + arow * 512 + krow;
                bf16x8 ah[16];
                #pragma unroll
                for (int ks = 0; ks < 16; ++ks) ah[ks] = *(const bf16x8*)(hp + ks * 32);
                #pragma unroll
                for (int ks = 0; ks < 16; ++ks) {
                    acc0 = __builtin_amdgcn_mfma_f32_16x16x32_bf16(ah[ks], whhF[ks][0], acc0, 0, 0, 0);
                    acc1 = __builtin_amdgcn_mfma_f32_16x16x32_bf16(ah[ks], whhF[ks][1], acc1, 0, 0, 0);
                }
            }

            // bias + L0 input projection (f32, registers)
            #pragma unroll
            for (int r = 0; r < 4; ++r) { acc0[r] += bias0; acc1[r] += bias1; }
            if (L == 0) {
                #pragma unroll
                for (int r = 0; r < 4; ++r) {
                    float s0 = 0.f, s1 = 0.f;
                    #pragma unroll
                    for (int d = 0; d < 6; ++d) {
                        s0 += w0a[d] * xv[r][d];
                        s1 += w0b[d] * xv[r][d];
                    }
                    acc0[r] += s0; acc1[r] += s1;
                }
            }

            // lane l (hi8==0) holds gates i (acc0) and g (acc1) for j=wg*8+jl;
            // lane l^8 holds f and o for the same j -> one xor-8 shuffle round.
            #pragma unroll
            for (int r = 0; r < 4; ++r) {
                float fo0 = __shfl_xor(acc0[r], 8, 64);  // lo lanes receive f
                float fo1 = __shfl_xor(acc1[r], 8, 64);  // lo lanes receive o
                if (hi8 == 0) {
                    float ii = sigm(acc0[r]), gg = tanh_(acc1[r]);
                    float ff = sigm(fo0),    oo = sigm(fo1);
                    float c = ff * cstv[r] + ii * gg;
                    cstv[r] = c;
                    float h = oo * tanh_(c);
                    int b = rowbase + kq * 4 + r;
                    int j = wg * 8 + jl;
                    ushort hb = f2bf(h);
                    if (L == 2) {
                        h2ring[(size_t)(t & 1) * HSLICE + b * 512 + j] = hb;
                        if ((t & 7) == 7)
                            ybuf[(size_t)(t >> 3) * HSLICE + b * 512 + j] = hb;
                    } else {
                        hout[(size_t)(t & (RING - 1)) * HSLICE + b * 512 + j] = hb;
                    }
                }
            }
        }

        // publish: all waves' stores drained (syncthreads), then one release
        // store to this block's own flag line (no RMW contention anywhere).
        __syncthreads();
        if (tid == 0 && s < S_TOTAL - 1)
            __hip_atomic_store(flags + blk * 32, (uint)(s + 1),
                               __ATOMIC_RELEASE, __HIP_MEMORY_SCOPE_AGENT);
    }
}

// ---- final projection: out[8192][256] = y[8192][512] @ w_out^T + b_out ---

__global__ __launch_bounds__(256, 1)
void out_gemm(const ushort* __restrict__ y, const float* __restrict__ wout,
              const float* __restrict__ bout, float* __restrict__ out) {
    __shared__ ushort Bl[64 * 512];  // 64 output cols x 512, bf16 swizzled
    const int bm = blockIdx.x;       // 128 m-tiles of 64 rows
    const int bn = blockIdx.y;       // 4 n-tiles of 64 cols
    const int tid = threadIdx.x, wv = tid >> 6, l = tid & 63;

    #pragma unroll
    for (int i = 0; i < 16; ++i) {
        int c = tid + 256 * i;
        int n = c >> 6;
        int kE = (c & 63) << 3;
        const float* s = wout + (size_t)(bn * 64 + n) * 512 + kE;
        float4 f0 = *(const float4*)s;
        float4 f1 = *(const float4*)(s + 4);
        uint4 v;
        v.x = (uint)f2bf(f0.x) | ((uint)f2bf(f0.y) << 16);
        v.y = (uint)f2bf(f0.z) | ((uint)f2bf(f0.w) << 16);
        v.z = (uint)f2bf(f1.x) | ((uint)f2bf(f1.y) << 16);
        v.w = (uint)f2bf(f1.z) | ((uint)f2bf(f1.w) << 16);
        *(uint4*)(Bl + swzE(n, kE)) = v;
    }
    __syncthreads();

    const int m0 = bm * 64 + (wv << 4);
    const int arow = m0 + (l & 15);
    const int koff = (l >> 4) << 3;
    f32x4 acc[4] = {{0.f,0.f,0.f,0.f},{0.f,0.f,0.f,0.f},{0.f,0.f,0.f,0.f},{0.f,0.f,0.f,0.f}};
    for (int ks = 0; ks < 16; ++ks) {
        int k = (ks << 5) + koff;
        bf16x8 a = *(const bf16x8*)(y + (size_t)arow * 512 + k);
        #pragma unroll
        for (int nt = 0; nt < 4; ++nt) {
            bf16x8 b = *(const bf16x8*)(Bl + swzE((nt << 4) + (l & 15), k));
            acc[nt] = __builtin_amdgcn_mfma_f32_16x16x32_bf16(a, b, acc[nt], 0, 0, 0);
        }
    }
    const int r0 = (l >> 4) << 2;
    #pragma unroll
    for (int nt = 0; nt < 4; ++nt) {
        int n = bn * 64 + (nt << 4) + (l & 15);
        float bo = bout[n];
        #pragma unroll
        for (int r = 0; r < 4; ++r) {
            int m = m0 + r0 + r;
            out[(size_t)m * 256 + n] = acc[nt][r] + bo;
        }
    }
}

// ---- launch --------------------------------------------------------------

extern "C" void kernel_launch(void* const* d_in, const int* in_sizes, int n_in,
                              void* d_out, int out_size, void* d_ws, size_t ws_size,
                              hipStream_t stream) {
    const float* feat = (const float*)d_in[0];
    const float* wih0 = (const float*)d_in[1];
    const float* whh0 = (const float*)d_in[2];
    const float* bih0 = (const float*)d_in[3];
    const float* bhh0 = (const float*)d_in[4];
    const float* wih1 = (const float*)d_in[5];
    const float* whh1 = (const float*)d_in[6];
    const float* bih1 = (const float*)d_in[7];
    const float* bhh1 = (const float*)d_in[8];
    const float* wih2 = (const float*)d_in[9];
    const float* whh2 = (const float*)d_in[10];
    const float* bih2 = (const float*)d_in[11];
    const float* bhh2 = (const float*)d_in[12];
    const float* wout = (const float*)d_in[13];
    const float* bout = (const float*)d_in[14];

    char* ws = (char*)d_ws;
    uint*   flags = (uint*)ws;                              // 192 x 128B lines
    ushort* h0    = (ushort*)(ws + 32768);                  // RING x 64KB
    ushort* h1    = h0 + (size_t)RING * HSLICE;             // RING x 64KB
    ushort* h2r   = h1 + (size_t)RING * HSLICE;             // 2 x 64KB
    ushort* ybuf  = h2r + (size_t)2 * HSLICE;               // 128 x 64KB = 8MB
    float*  out   = (float*)d_out;

    (void)hipMemsetAsync(flags, 0, 32768, stream);

    hipLaunchKernelGGL(lstm_scan, dim3(NWG), dim3(THREADS), 0, stream,
                       feat, wih0, whh0, bih0, bhh0, wih1, whh1, bih1, bhh1,
                       wih2, whh2, bih2, bhh2, h0, h1, h2r, ybuf, flags);

    hipLaunchKernelGGL(out_gemm, dim3(128, 4), dim3(256), 0, stream,
                       ybuf, wout, bout, out);
}

// Round 8
// 10643.254 us; speedup vs baseline: 1.2855x; 1.2855x over previous
//
#include <hip/hip_runtime.h>
#include <stdint.h>

#define T_STEPS 1024
#define NWG 192
#define THREADS 256
#define S_TOTAL (T_STEPS + 2)   // 3-layer pipeline skew
#define HSLICE (64 * 512)       // one timestep of h, elements
#define RING 4                  // h0/h1 ring slots (lockstep -> safe)

typedef __attribute__((ext_vector_type(8))) short bf16x8;
typedef __attribute__((ext_vector_type(4))) float f32x4;
typedef unsigned int uint;
typedef unsigned short ushort;
typedef unsigned long long u64;

// ---- helpers -------------------------------------------------------------

__device__ __forceinline__ ushort f2bf(float f) {  // RNE float->bf16
    uint u = __builtin_bit_cast(uint, f);
    u = (u + 0x7FFFu + ((u >> 16) & 1u)) >> 16;
    return (ushort)u;
}

__device__ __forceinline__ float sigm(float x) {
    x = fminf(fmaxf(x, -30.f), 30.f);
    return 1.f / (1.f + __expf(-x));
}

__device__ __forceinline__ float tanh_(float x) {
    x = fminf(fmaxf(x, -15.f), 15.f);
    float e = __expf(2.f * x);
    return (e - 1.f) / (e + 1.f);
}

__device__ __forceinline__ bf16x8 packW(const float* __restrict__ p) {
    float4 a = *(const float4*)p, b = *(const float4*)(p + 4);
    bf16x8 r;
    r[0] = (short)f2bf(a.x); r[1] = (short)f2bf(a.y);
    r[2] = (short)f2bf(a.z); r[3] = (short)f2bf(a.w);
    r[4] = (short)f2bf(b.x); r[5] = (short)f2bf(b.y);
    r[6] = (short)f2bf(b.z); r[7] = (short)f2bf(b.w);
    return r;
}

// LLC-coherent (agent-scope relaxed) 8B load / 4B store: sc0+sc1, bypass
// L1/L2, no cache-maintenance ops. This is the whole point of this round.
__device__ __forceinline__ u64 ald(const u64* p) {
    return __hip_atomic_load(p, __ATOMIC_RELAXED, __HIP_MEMORY_SCOPE_AGENT);
}
__device__ __forceinline__ void ast(uint* p, uint v) {
    __hip_atomic_store(p, v, __ATOMIC_RELAXED, __HIP_MEMORY_SCOPE_AGENT);
}
__device__ __forceinline__ bf16x8 mk(u64 lo, u64 hi) {
    union { u64 q[2]; bf16x8 v; } u; u.q[0] = lo; u.q[1] = hi; return u.v;
}

// swizzle for out_gemm's B tile only
__device__ __forceinline__ int swzE(int row, int k) {
    return row * 512 + (k ^ ((row & 7) << 3));
}

// ---- persistent 3-layer pipelined scan ----------------------------------
// Weights in VGPRs, cell state in VGPRs, zero LDS in the loop.
// Cross-block h exchange rides the LLC via relaxed agent atomics; the
// pre-barrier s_waitcnt vmcnt(0) (implicit in __syncthreads) is the only
// ordering needed before the flag publish. No release/acquire -> no
// buffer_wbl2 / buffer_inv per step.

__global__ __launch_bounds__(THREADS, 1)
void lstm_scan(const float* __restrict__ feat,
               const float* __restrict__ wih0, const float* __restrict__ whh0,
               const float* __restrict__ bih0, const float* __restrict__ bhh0,
               const float* __restrict__ wih1, const float* __restrict__ whh1,
               const float* __restrict__ bih1, const float* __restrict__ bhh1,
               const float* __restrict__ wih2, const float* __restrict__ whh2,
               const float* __restrict__ bih2, const float* __restrict__ bhh2,
               ushort* h0buf, ushort* h1buf, ushort* h2ring, ushort* ybuf,
               uint* flags) {
    const int blk = blockIdx.x, L = blk >> 6, wg = blk & 63;
    const int tid = threadIdx.x, wv = tid >> 6, l = tid & 63;
    const int c16 = l & 15, hi8 = c16 >> 3, jl = c16 & 7, kq = l >> 4;
    const int krow = kq * 8;
    const int rowbase = wv * 16;        // D rows rowbase + kq*4 + r
    const int arow = rowbase + c16;     // A-fragment row (batch)

    const float* wih_g = (L == 0) ? wih0 : (L == 1) ? wih1 : wih2;
    const float* whh_g = (L == 0) ? whh0 : (L == 1) ? whh1 : whh2;
    const float* bih_g = (L == 0) ? bih0 : (L == 1) ? bih1 : bih2;
    const float* bhh_g = (L == 0) ? bhh0 : (L == 1) ? bhh1 : bhh2;
    const ushort* xsrc = (L == 1) ? h0buf : (L == 2) ? h1buf : nullptr;
    ushort* hout = (L == 0) ? h0buf : (L == 1) ? h1buf : nullptr;  // L2: ring

    // col-tile 0 -> gate hi8 (i/f), col-tile 1 -> gate 2+hi8 (g/o)
    const int gcol0 = hi8 * 512 + wg * 8 + jl;
    const int gcol1 = (2 + hi8) * 512 + wg * 8 + jl;

    // ---- weights -> registers (one-time, normal cached loads) ----
    bf16x8 whhF[16][2];
    #pragma unroll
    for (int ks = 0; ks < 16; ++ks) {
        whhF[ks][0] = packW(whh_g + (size_t)gcol0 * 512 + ks * 32 + krow);
        whhF[ks][1] = packW(whh_g + (size_t)gcol1 * 512 + ks * 32 + krow);
    }
    bf16x8 wihF[16][2];
    if (L > 0) {
        #pragma unroll
        for (int ks = 0; ks < 16; ++ks) {
            wihF[ks][0] = packW(wih_g + (size_t)gcol0 * 512 + ks * 32 + krow);
            wihF[ks][1] = packW(wih_g + (size_t)gcol1 * 512 + ks * 32 + krow);
        }
    }
    const float bias0 = bih_g[gcol0] + bhh_g[gcol0];
    const float bias1 = bih_g[gcol1] + bhh_g[gcol1];
    float w0a[6], w0b[6];
    if (L == 0) {
        #pragma unroll
        for (int d = 0; d < 6; ++d) {
            w0a[d] = wih0[gcol0 * 6 + d];
            w0b[d] = wih0[gcol1 * 6 + d];
        }
    }
    f32x4 cstv = {0.f, 0.f, 0.f, 0.f};   // cell state; lo lanes own (4 b, j)

    for (int s = 0; s < S_TOTAL; ++s) {
        const int t = s - L;

        // feat prefetch: cached loads, independent of the barrier, and never
        // invalidated now -> L1/L2 hits after the first pass.
        float xv[4][6];
        if (L == 0 && t >= 0 && t < T_STEPS) {
            #pragma unroll
            for (int r = 0; r < 4; ++r)
                #pragma unroll
                for (int d = 0; d < 6; ++d)
                    xv[r][d] = feat[(size_t)((rowbase + kq * 4 + r) * 6 + d) * T_STEPS + t];
        }

        // ---- flag-array barrier: wait for all blocks to finish step s-1 ----
        if (s > 0) {
            for (;;) {
                int ok = 1;
                if (tid < NWG)
                    ok = (__hip_atomic_load(flags + tid * 32, __ATOMIC_RELAXED,
                                            __HIP_MEMORY_SCOPE_AGENT) >= (uint)s);
                if (__syncthreads_and(ok)) break;
                __builtin_amdgcn_s_sleep(2);
            }
        }

        if (t >= 0 && t < T_STEPS) {
            f32x4 acc0 = {0.f, 0.f, 0.f, 0.f};
            f32x4 acc1 = {0.f, 0.f, 0.f, 0.f};

            if (L > 0) {
                const u64* xp = (const u64*)(xsrc + (size_t)(t & (RING - 1)) * HSLICE
                                             + arow * 512 + krow);
                if (t > 0) {
                    const ushort* hsrc = (L == 2)
                        ? h2ring + (size_t)((t - 1) & 1) * HSLICE
                        : hout + (size_t)((t - 1) & (RING - 1)) * HSLICE;
                    const u64* hp = (const u64*)(hsrc + arow * 512 + krow);
                    f32x4 e0 = {0.f, 0.f, 0.f, 0.f}, e1 = {0.f, 0.f, 0.f, 0.f};
                    #pragma unroll
                    for (int ks = 0; ks < 16; ++ks) {
                        bf16x8 ax = mk(ald(xp + ks * 8), ald(xp + ks * 8 + 1));
                        bf16x8 ah = mk(ald(hp + ks * 8), ald(hp + ks * 8 + 1));
                        acc0 = __builtin_amdgcn_mfma_f32_16x16x32_bf16(ax, wihF[ks][0], acc0, 0, 0, 0);
                        acc1 = __builtin_amdgcn_mfma_f32_16x16x32_bf16(ax, wihF[ks][1], acc1, 0, 0, 0);
                        e0   = __builtin_amdgcn_mfma_f32_16x16x32_bf16(ah, whhF[ks][0], e0, 0, 0, 0);
                        e1   = __builtin_amdgcn_mfma_f32_16x16x32_bf16(ah, whhF[ks][1], e1, 0, 0, 0);
                    }
                    acc0 += e0; acc1 += e1;
                } else {
                    #pragma unroll
                    for (int ks = 0; ks < 16; ++ks) {
                        bf16x8 ax = mk(ald(xp + ks * 8), ald(xp + ks * 8 + 1));
                        acc0 = __builtin_amdgcn_mfma_f32_16x16x32_bf16(ax, wihF[ks][0], acc0, 0, 0, 0);
                        acc1 = __builtin_amdgcn_mfma_f32_16x16x32_bf16(ax, wihF[ks][1], acc1, 0, 0, 0);
                    }
                }
            } else if (t > 0) {
                const u64* hp = (const u64*)(h0buf + (size_t)((t - 1) & (RING - 1)) * HSLICE
                                             + arow * 512 + krow);
                #pragma unroll
                for (int ks = 0; ks < 16; ++ks) {
                    bf16x8 ah = mk(ald(hp + ks * 8), ald(hp + ks * 8 + 1));
                    acc0 = __builtin_amdgcn_mfma_f32_16x16x32_bf16(ah, whhF[ks][0], acc0, 0, 0, 0);
                    acc1 = __builtin_amdgcn_mfma_f32_16x16x32_bf16(ah, whhF[ks][1], acc1, 0, 0, 0);
                }
            }

            // bias + L0 input projection (f32, registers)
            #pragma unroll
            for (int r = 0; r < 4; ++r) { acc0[r] += bias0; acc1[r] += bias1; }
            if (L == 0) {
                #pragma unroll
                for (int r = 0; r < 4; ++r) {
                    float s0 = 0.f, s1 = 0.f;
                    #pragma unroll
                    for (int d = 0; d < 6; ++d) {
                        s0 += w0a[d] * xv[r][d];
                        s1 += w0b[d] * xv[r][d];
                    }
                    acc0[r] += s0; acc1[r] += s1;
                }
            }

            // lo lanes hold i (acc0) and g (acc1) for j=wg*8+jl; lane l^8
            // holds f and o -> one xor-8 shuffle; then pair j/j+1 via xor-1
            // so stores are 4B words on the LLC path.
            #pragma unroll
            for (int r = 0; r < 4; ++r) {
                float fo0 = __shfl_xor(acc0[r], 8, 64);
                float fo1 = __shfl_xor(acc1[r], 8, 64);
                uint hv = 0;
                if (hi8 == 0) {
                    float ii = sigm(acc0[r]), gg = tanh_(acc1[r]);
                    float ff = sigm(fo0),    oo = sigm(fo1);
                    float c = ff * cstv[r] + ii * gg;
                    cstv[r] = c;
                    hv = (uint)f2bf(oo * tanh_(c));
                }
                uint other = __shfl_xor(hv, 1, 64);
                if (hi8 == 0 && !(jl & 1)) {
                    uint word = hv | (other << 16);
                    int b = rowbase + kq * 4 + r;
                    int j = wg * 8 + jl;
                    if (L == 2) {
                        ast((uint*)&h2ring[(size_t)(t & 1) * HSLICE + b * 512 + j], word);
                        if ((t & 7) == 7)
                            *(uint*)&ybuf[(size_t)(t >> 3) * HSLICE + b * 512 + j] = word;
                    } else {
                        ast((uint*)&hout[(size_t)(t & (RING - 1)) * HSLICE + b * 512 + j], word);
                    }
                }
            }
        }

        // publish: __syncthreads' implicit s_waitcnt vmcnt(0) drains every
        // thread's LLC stores; then one relaxed flag store (own 128B line).
        __syncthreads();
        if (tid == 0 && s < S_TOTAL - 1)
            ast(flags + blk * 32, (uint)(s + 1));
    }
}

// ---- final projection: out[8192][256] = y[8192][512] @ w_out^T + b_out ---

__global__ __launch_bounds__(256, 1)
void out_gemm(const ushort* __restrict__ y, const float* __restrict__ wout,
              const float* __restrict__ bout, float* __restrict__ out) {
    __shared__ ushort Bl[64 * 512];  // 64 output cols x 512, bf16 swizzled
    const int bm = blockIdx.x;       // 128 m-tiles of 64 rows
    const int bn = blockIdx.y;       // 4 n-tiles of 64 cols
    const int tid = threadIdx.x, wv = tid >> 6, l = tid & 63;

    #pragma unroll
    for (int i = 0; i < 16; ++i) {
        int c = tid + 256 * i;
        int n = c >> 6;
        int kE = (c & 63) << 3;
        const float* s = wout + (size_t)(bn * 64 + n) * 512 + kE;
        float4 f0 = *(const float4*)s;
        float4 f1 = *(const float4*)(s + 4);
        uint4 v;
        v.x = (uint)f2bf(f0.x) | ((uint)f2bf(f0.y) << 16);
        v.y = (uint)f2bf(f0.z) | ((uint)f2bf(f0.w) << 16);
        v.z = (uint)f2bf(f1.x) | ((uint)f2bf(f1.y) << 16);
        v.w = (uint)f2bf(f1.z) | ((uint)f2bf(f1.w) << 16);
        *(uint4*)(Bl + swzE(n, kE)) = v;
    }
    __syncthreads();

    const int m0 = bm * 64 + (wv << 4);
    const int arow = m0 + (l & 15);
    const int koff = (l >> 4) << 3;
    f32x4 acc[4] = {{0.f,0.f,0.f,0.f},{0.f,0.f,0.f,0.f},{0.f,0.f,0.f,0.f},{0.f,0.f,0.f,0.f}};
    for (int ks = 0; ks < 16; ++ks) {
        int k = (ks << 5) + koff;
        bf16x8 a = *(const bf16x8*)(y + (size_t)arow * 512 + k);
        #pragma unroll
        for (int nt = 0; nt < 4; ++nt) {
            bf16x8 b = *(const bf16x8*)(Bl + swzE((nt << 4) + (l & 15), k));
            acc[nt] = __builtin_amdgcn_mfma_f32_16x16x32_bf16(a, b, acc[nt], 0, 0, 0);
        }
    }
    const int r0 = (l >> 4) << 2;
    #pragma unroll
    for (int nt = 0; nt < 4; ++nt) {
        int n = bn * 64 + (nt << 4) + (l & 15);
        float bo = bout[n];
        #pragma unroll
        for (int r = 0; r < 4; ++r) {
            int m = m0 + r0 + r;
            out[(size_t)m * 256 + n] = acc[nt][r] + bo;
        }
    }
}

// ---- launch --------------------------------------------------------------

extern "C" void kernel_launch(void* const* d_in, const int* in_sizes, int n_in,
                              void* d_out, int out_size, void* d_ws, size_t ws_size,
                              hipStream_t stream) {
    const float* feat = (const float*)d_in[0];
    const float* wih0 = (const float*)d_in[1];
    const float* whh0 = (const float*)d_in[2];
    const float* bih0 = (const float*)d_in[3];
    const float* bhh0 = (const float*)d_in[4];
    const float* wih1 = (const float*)d_in[5];
    const float* whh1 = (const float*)d_in[6];
    const float* bih1 = (const float*)d_in[7];
    const float* bhh1 = (const float*)d_in[8];
    const float* wih2 = (const float*)d_in[9];
    const float* whh2 = (const float*)d_in[10];
    const float* bih2 = (const float*)d_in[11];
    const float* bhh2 = (const float*)d_in[12];
    const float* wout = (const float*)d_in[13];
    const float* bout = (const float*)d_in[14];

    char* ws = (char*)d_ws;
    uint*   flags = (uint*)ws;                              // 192 x 128B lines
    ushort* h0    = (ushort*)(ws + 32768);                  // RING x 64KB
    ushort* h1    = h0 + (size_t)RING * HSLICE;             // RING x 64KB
    ushort* h2r   = h1 + (size_t)RING * HSLICE;             // 2 x 64KB
    ushort* ybuf  = h2r + (size_t)2 * HSLICE;               // 128 x 64KB = 8MB
    float*  out   = (float*)d_out;

    (void)hipMemsetAsync(flags, 0, 32768, stream);

    hipLaunchKernelGGL(lstm_scan, dim3(NWG), dim3(THREADS), 0, stream,
                       feat, wih0, whh0, bih0, bhh0, wih1, whh1, bih1, bhh1,
                       wih2, whh2, bih2, bhh2, h0, h1, h2r, ybuf, flags);

    hipLaunchKernelGGL(out_gemm, dim3(128, 4), dim3(256), 0, stream,
                       ybuf, wout, bout, out);
}

// Round 9
// 10183.662 us; speedup vs baseline: 1.3435x; 1.0451x over previous
//
#include <hip/hip_runtime.h>
#include <stdint.h>

#define T_STEPS 1024
#define NWG 192
#define THREADS 256
#define HSLICE (64 * 512)       // one timestep of h, elements
#define RING 4                  // h0/h1 ring slots; backpressure thr = t-3
#define NEG_INF (-1000000)

typedef __attribute__((ext_vector_type(8))) short bf16x8;
typedef __attribute__((ext_vector_type(4))) float f32x4;
typedef unsigned int uint;
typedef unsigned short ushort;
typedef unsigned long long u64;

// ---- helpers -------------------------------------------------------------

__device__ __forceinline__ ushort f2bf(float f) {  // RNE float->bf16
    uint u = __builtin_bit_cast(uint, f);
    u = (u + 0x7FFFu + ((u >> 16) & 1u)) >> 16;
    return (ushort)u;
}

__device__ __forceinline__ float sigm(float x) {
    x = fminf(fmaxf(x, -30.f), 30.f);
    return 1.f / (1.f + __expf(-x));
}

__device__ __forceinline__ float tanh_(float x) {
    x = fminf(fmaxf(x, -15.f), 15.f);
    float e = __expf(2.f * x);
    return (e - 1.f) / (e + 1.f);
}

__device__ __forceinline__ bf16x8 packW(const float* __restrict__ p) {
    float4 a = *(const float4*)p, b = *(const float4*)(p + 4);
    bf16x8 r;
    r[0] = (short)f2bf(a.x); r[1] = (short)f2bf(a.y);
    r[2] = (short)f2bf(a.z); r[3] = (short)f2bf(a.w);
    r[4] = (short)f2bf(b.x); r[5] = (short)f2bf(b.y);
    r[6] = (short)f2bf(b.z); r[7] = (short)f2bf(b.w);
    return r;
}

// LLC-coherent (agent-scope relaxed) 8B load / 4B store: bypass L1/L2,
// no cache-maintenance ops (no wbl2/inv). Proven correct rounds 5-8.
__device__ __forceinline__ u64 ald(const u64* p) {
    return __hip_atomic_load(p, __ATOMIC_RELAXED, __HIP_MEMORY_SCOPE_AGENT);
}
__device__ __forceinline__ void ast(uint* p, uint v) {
    __hip_atomic_store(p, v, __ATOMIC_RELAXED, __HIP_MEMORY_SCOPE_AGENT);
}
__device__ __forceinline__ bf16x8 mk(u64 lo, u64 hi) {
    union { u64 q[2]; bf16x8 v; } u; u.q[0] = lo; u.q[1] = hi; return u.v;
}

// swizzle for out_gemm's B tile only
__device__ __forceinline__ int swzE(int row, int k) {
    return row * 512 + (k ^ ((row & 7) << 3));
}

// ---- persistent 3-layer DECOUPLED pipeline scan --------------------------
// No global barrier. flags[blk] = #steps completed by block blk. Block of
// layer L at local step t waits for:
//   layer L-1 flags >= t+1   (x-tile produced)
//   layer L   flags >= t     (own-layer h[t-1] produced; also h2 ring safety)
//   layer L+1 flags >= t-3   (RING=4 slot about to be overwritten consumed)
// Steady state: producers run ahead -> first poll round succeeds; cross-layer
// latency is a constant pipeline offset, not a per-step cost.

__global__ __launch_bounds__(THREADS, 1)
void lstm_scan(const float* __restrict__ feat,
               const float* __restrict__ wih0, const float* __restrict__ whh0,
               const float* __restrict__ bih0, const float* __restrict__ bhh0,
               const float* __restrict__ wih1, const float* __restrict__ whh1,
               const float* __restrict__ bih1, const float* __restrict__ bhh1,
               const float* __restrict__ wih2, const float* __restrict__ whh2,
               const float* __restrict__ bih2, const float* __restrict__ bhh2,
               ushort* h0buf, ushort* h1buf, ushort* h2ring, ushort* ybuf,
               uint* flags) {
    const int blk = blockIdx.x, L = blk >> 6, wg = blk & 63;
    const int tid = threadIdx.x, wv = tid >> 6, l = tid & 63;
    const int c16 = l & 15, hi8 = c16 >> 3, jl = c16 & 7, kq = l >> 4;
    const int krow = kq * 8;
    const int rowbase = wv * 16;        // D rows rowbase + kq*4 + r
    const int arow = rowbase + c16;     // A-fragment row (batch)

    const float* wih_g = (L == 0) ? wih0 : (L == 1) ? wih1 : wih2;
    const float* whh_g = (L == 0) ? whh0 : (L == 1) ? whh1 : whh2;
    const float* bih_g = (L == 0) ? bih0 : (L == 1) ? bih1 : bih2;
    const float* bhh_g = (L == 0) ? bhh0 : (L == 1) ? bhh1 : bhh2;
    const ushort* xsrc = (L == 1) ? h0buf : (L == 2) ? h1buf : nullptr;
    ushort* hout = (L == 0) ? h0buf : (L == 1) ? h1buf : nullptr;  // L2: ring

    // col-tile 0 -> gate hi8 (i/f), col-tile 1 -> gate 2+hi8 (g/o)
    const int gcol0 = hi8 * 512 + wg * 8 + jl;
    const int gcol1 = (2 + hi8) * 512 + wg * 8 + jl;

    // ---- weights -> registers (one-time, normal cached loads) ----
    bf16x8 whhF[16][2];
    #pragma unroll
    for (int ks = 0; ks < 16; ++ks) {
        whhF[ks][0] = packW(whh_g + (size_t)gcol0 * 512 + ks * 32 + krow);
        whhF[ks][1] = packW(whh_g + (size_t)gcol1 * 512 + ks * 32 + krow);
    }
    bf16x8 wihF[16][2];
    if (L > 0) {
        #pragma unroll
        for (int ks = 0; ks < 16; ++ks) {
            wihF[ks][0] = packW(wih_g + (size_t)gcol0 * 512 + ks * 32 + krow);
            wihF[ks][1] = packW(wih_g + (size_t)gcol1 * 512 + ks * 32 + krow);
        }
    }
    const float bias0 = bih_g[gcol0] + bhh_g[gcol0];
    const float bias1 = bih_g[gcol1] + bhh_g[gcol1];
    float w0a[6], w0b[6];
    if (L == 0) {
        #pragma unroll
        for (int d = 0; d < 6; ++d) {
            w0a[d] = wih0[gcol0 * 6 + d];
            w0b[d] = wih0[gcol1 * 6 + d];
        }
    }
    f32x4 cstv = {0.f, 0.f, 0.f, 0.f};   // cell state; lo lanes own (4 b, j)

    for (int t = 0; t < T_STEPS; ++t) {
        // feat prefetch: cached loads, independent of flags -> issue early
        float xv[4][6];
        if (L == 0) {
            #pragma unroll
            for (int r = 0; r < 4; ++r)
                #pragma unroll
                for (int d = 0; d < 6; ++d)
                    xv[r][d] = feat[(size_t)((rowbase + kq * 4 + r) * 6 + d) * T_STEPS + t];
        }

        // ---- decoupled flow-control poll ----
        {
            int thr = NEG_INF;
            if (tid < NWG) {
                int g = tid >> 6;  // layer owning flag tid
                if (L == 0)      thr = (g == 0) ? t     : (g == 1) ? t - 3 : NEG_INF;
                else if (L == 1) thr = (g == 0) ? t + 1 : (g == 1) ? t     : t - 3;
                else             thr = (g == 1) ? t + 1 : (g == 2) ? t     : NEG_INF;
            }
            if (thr > 0) {  // thresholds <=0 auto-satisfied (flags start at 0)
                for (;;) {
                    int ok = ((int)__hip_atomic_load(flags + tid * 32, __ATOMIC_RELAXED,
                                                     __HIP_MEMORY_SCOPE_AGENT) >= thr);
                    if (__syncthreads_and(ok)) break;
                    __builtin_amdgcn_s_sleep(4);
                }
            } else {
                for (;;) { if (__syncthreads_and(1)) break; }  // keep barrier symmetry
            }
        }

        {
            f32x4 acc0 = {0.f, 0.f, 0.f, 0.f};
            f32x4 acc1 = {0.f, 0.f, 0.f, 0.f};

            if (L > 0) {
                const u64* xp = (const u64*)(xsrc + (size_t)(t & (RING - 1)) * HSLICE
                                             + arow * 512 + krow);
                if (t > 0) {
                    const ushort* hsrc = (L == 2)
                        ? h2ring + (size_t)((t - 1) & 1) * HSLICE
                        : hout + (size_t)((t - 1) & (RING - 1)) * HSLICE;
                    const u64* hp = (const u64*)(hsrc + arow * 512 + krow);
                    f32x4 e0 = {0.f, 0.f, 0.f, 0.f}, e1 = {0.f, 0.f, 0.f, 0.f};
                    #pragma unroll
                    for (int ks = 0; ks < 16; ++ks) {
                        bf16x8 ax = mk(ald(xp + ks * 8), ald(xp + ks * 8 + 1));
                        bf16x8 ah = mk(ald(hp + ks * 8), ald(hp + ks * 8 + 1));
                        acc0 = __builtin_amdgcn_mfma_f32_16x16x32_bf16(ax, wihF[ks][0], acc0, 0, 0, 0);
                        acc1 = __builtin_amdgcn_mfma_f32_16x16x32_bf16(ax, wihF[ks][1], acc1, 0, 0, 0);
                        e0   = __builtin_amdgcn_mfma_f32_16x16x32_bf16(ah, whhF[ks][0], e0, 0, 0, 0);
                        e1   = __builtin_amdgcn_mfma_f32_16x16x32_bf16(ah, whhF[ks][1], e1, 0, 0, 0);
                    }
                    acc0 += e0; acc1 += e1;
                } else {
                    #pragma unroll
                    for (int ks = 0; ks < 16; ++ks) {
                        bf16x8 ax = mk(ald(xp + ks * 8), ald(xp + ks * 8 + 1));
                        acc0 = __builtin_amdgcn_mfma_f32_16x16x32_bf16(ax, wihF[ks][0], acc0, 0, 0, 0);
                        acc1 = __builtin_amdgcn_mfma_f32_16x16x32_bf16(ax, wihF[ks][1], acc1, 0, 0, 0);
                    }
                }
            } else if (t > 0) {
                const u64* hp = (const u64*)(h0buf + (size_t)((t - 1) & (RING - 1)) * HSLICE
                                             + arow * 512 + krow);
                #pragma unroll
                for (int ks = 0; ks < 16; ++ks) {
                    bf16x8 ah = mk(ald(hp + ks * 8), ald(hp + ks * 8 + 1));
                    acc0 = __builtin_amdgcn_mfma_f32_16x16x32_bf16(ah, whhF[ks][0], acc0, 0, 0, 0);
                    acc1 = __builtin_amdgcn_mfma_f32_16x16x32_bf16(ah, whhF[ks][1], acc1, 0, 0, 0);
                }
            }

            // bias + L0 input projection (f32, registers)
            #pragma unroll
            for (int r = 0; r < 4; ++r) { acc0[r] += bias0; acc1[r] += bias1; }
            if (L == 0) {
                #pragma unroll
                for (int r = 0; r < 4; ++r) {
                    float s0 = 0.f, s1 = 0.f;
                    #pragma unroll
                    for (int d = 0; d < 6; ++d) {
                        s0 += w0a[d] * xv[r][d];
                        s1 += w0b[d] * xv[r][d];
                    }
                    acc0[r] += s0; acc1[r] += s1;
                }
            }

            // lo lanes hold i (acc0) and g (acc1) for j=wg*8+jl; lane l^8
            // holds f and o -> one xor-8 shuffle; then pair j/j+1 via xor-1
            // so stores are 4B words on the LLC path.
            #pragma unroll
            for (int r = 0; r < 4; ++r) {
                float fo0 = __shfl_xor(acc0[r], 8, 64);
                float fo1 = __shfl_xor(acc1[r], 8, 64);
                uint hv = 0;
                if (hi8 == 0) {
                    float ii = sigm(acc0[r]), gg = tanh_(acc1[r]);
                    float ff = sigm(fo0),    oo = sigm(fo1);
                    float c = ff * cstv[r] + ii * gg;
                    cstv[r] = c;
                    hv = (uint)f2bf(oo * tanh_(c));
                }
                uint other = __shfl_xor(hv, 1, 64);
                if (hi8 == 0 && !(jl & 1)) {
                    uint word = hv | (other << 16);
                    int b = rowbase + kq * 4 + r;
                    int j = wg * 8 + jl;
                    if (L == 2) {
                        ast((uint*)&h2ring[(size_t)(t & 1) * HSLICE + b * 512 + j], word);
                        if ((t & 7) == 7)
                            *(uint*)&ybuf[(size_t)(t >> 3) * HSLICE + b * 512 + j] = word;
                    } else {
                        ast((uint*)&hout[(size_t)(t & (RING - 1)) * HSLICE + b * 512 + j], word);
                    }
                }
            }
        }

        // publish: __syncthreads' per-wave s_waitcnt vmcnt(0) drains all LLC
        // stores; then one relaxed flag store on this block's own 128B line.
        __syncthreads();
        if (tid == 0)
            ast(flags + blk * 32, (uint)(t + 1));
    }
}

// ---- final projection: out[8192][256] = y[8192][512] @ w_out^T + b_out ---

__global__ __launch_bounds__(256, 1)
void out_gemm(const ushort* __restrict__ y, const float* __restrict__ wout,
              const float* __restrict__ bout, float* __restrict__ out) {
    __shared__ ushort Bl[64 * 512];  // 64 output cols x 512, bf16 swizzled
    const int bm = blockIdx.x;       // 128 m-tiles of 64 rows
    const int bn = blockIdx.y;       // 4 n-tiles of 64 cols
    const int tid = threadIdx.x, wv = tid >> 6, l = tid & 63;

    #pragma unroll
    for (int i = 0; i < 16; ++i) {
        int c = tid + 256 * i;
        int n = c >> 6;
        int kE = (c & 63) << 3;
        const float* s = wout + (size_t)(bn * 64 + n) * 512 + kE;
        float4 f0 = *(const float4*)s;
        float4 f1 = *(const float4*)(s + 4);
        uint4 v;
        v.x = (uint)f2bf(f0.x) | ((uint)f2bf(f0.y) << 16);
        v.y = (uint)f2bf(f0.z) | ((uint)f2bf(f0.w) << 16);
        v.z = (uint)f2bf(f1.x) | ((uint)f2bf(f1.y) << 16);
        v.w = (uint)f2bf(f1.z) | ((uint)f2bf(f1.w) << 16);
        *(uint4*)(Bl + swzE(n, kE)) = v;
    }
    __syncthreads();

    const int m0 = bm * 64 + (wv << 4);
    const int arow = m0 + (l & 15);
    const int koff = (l >> 4) << 3;
    f32x4 acc[4] = {{0.f,0.f,0.f,0.f},{0.f,0.f,0.f,0.f},{0.f,0.f,0.f,0.f},{0.f,0.f,0.f,0.f}};
    for (int ks = 0; ks < 16; ++ks) {
        int k = (ks << 5) + koff;
        bf16x8 a = *(const bf16x8*)(y + (size_t)arow * 512 + k);
        #pragma unroll
        for (int nt = 0; nt < 4; ++nt) {
            bf16x8 b = *(const bf16x8*)(Bl + swzE((nt << 4) + (l & 15), k));
            acc[nt] = __builtin_amdgcn_mfma_f32_16x16x32_bf16(a, b, acc[nt], 0, 0, 0);
        }
    }
    const int r0 = (l >> 4) << 2;
    #pragma unroll
    for (int nt = 0; nt < 4; ++nt) {
        int n = bn * 64 + (nt << 4) + (l & 15);
        float bo = bout[n];
        #pragma unroll
        for (int r = 0; r < 4; ++r) {
            int m = m0 + r0 + r;
            out[(size_t)m * 256 + n] = acc[nt][r] + bo;
        }
    }
}

// ---- launch --------------------------------------------------------------

extern "C" void kernel_launch(void* const* d_in, const int* in_sizes, int n_in,
                              void* d_out, int out_size, void* d_ws, size_t ws_size,
                              hipStream_t stream) {
    const float* feat = (const float*)d_in[0];
    const float* wih0 = (const float*)d_in[1];
    const float* whh0 = (const float*)d_in[2];
    const float* bih0 = (const float*)d_in[3];
    const float* bhh0 = (const float*)d_in[4];
    const float* wih1 = (const float*)d_in[5];
    const float* whh1 = (const float*)d_in[6];
    const float* bih1 = (const float*)d_in[7];
    const float* bhh1 = (const float*)d_in[8];
    const float* wih2 = (const float*)d_in[9];
    const float* whh2 = (const float*)d_in[10];
    const float* bih2 = (const float*)d_in[11];
    const float* bhh2 = (const float*)d_in[12];
    const float* wout = (const float*)d_in[13];
    const float* bout = (const float*)d_in[14];

    char* ws = (char*)d_ws;
    uint*   flags = (uint*)ws;                              // 192 x 128B lines
    ushort* h0    = (ushort*)(ws + 32768);                  // RING x 64KB
    ushort* h1    = h0 + (size_t)RING * HSLICE;             // RING x 64KB
    ushort* h2r   = h1 + (size_t)RING * HSLICE;             // 2 x 64KB
    ushort* ybuf  = h2r + (size_t)2 * HSLICE;               // 128 x 64KB = 8MB
    float*  out   = (float*)d_out;

    (void)hipMemsetAsync(flags, 0, 32768, stream);

    hipLaunchKernelGGL(lstm_scan, dim3(NWG), dim3(THREADS), 0, stream,
                       feat, wih0, whh0, bih0, bhh0, wih1, whh1, bih1, bhh1,
                       wih2, whh2, bih2, bhh2, h0, h1, h2r, ybuf, flags);

    hipLaunchKernelGGL(out_gemm, dim3(128, 4), dim3(256), 0, stream,
                       ybuf, wout, bout, out);
}

// Round 13
// 7533.646 us; speedup vs baseline: 1.8161x; 1.3518x over previous
//
#include <hip/hip_runtime.h>
#include <stdint.h>

#define T_STEPS 1024
#define NWG 192
#define THREADS 256
#define HSLICE (64 * 512)            // one timestep of h, elements
#define HSTRIDE (HSLICE + 64)        // +128B pad between slots (prefetch guard)
#define RING 4                       // ring size for fallback kernel
#define NEG_INF (-1000000)

typedef __attribute__((ext_vector_type(8))) short bf16x8;
typedef __attribute__((ext_vector_type(4))) float f32x4;
typedef unsigned int uint;
typedef unsigned short ushort;
typedef unsigned long long u64;

// ---- helpers -------------------------------------------------------------

__device__ __forceinline__ ushort f2bf(float f) {  // RNE float->bf16
    uint u = __builtin_bit_cast(uint, f);
    u = (u + 0x7FFFu + ((u >> 16) & 1u)) >> 16;
    return (ushort)u;
}

__device__ __forceinline__ float sigm(float x) {
    x = fminf(fmaxf(x, -30.f), 30.f);
    return 1.f / (1.f + __expf(-x));
}

__device__ __forceinline__ float tanh_(float x) {
    x = fminf(fmaxf(x, -15.f), 15.f);
    float e = __expf(2.f * x);
    return (e - 1.f) / (e + 1.f);
}

__device__ __forceinline__ bf16x8 packW(const float* __restrict__ p) {
    float4 a = *(const float4*)p, b = *(const float4*)(p + 4);
    bf16x8 r;
    r[0] = (short)f2bf(a.x); r[1] = (short)f2bf(a.y);
    r[2] = (short)f2bf(a.z); r[3] = (short)f2bf(a.w);
    r[4] = (short)f2bf(b.x); r[5] = (short)f2bf(b.y);
    r[6] = (short)f2bf(b.z); r[7] = (short)f2bf(b.w);
    return r;
}

// LLC-direct (agent-scope relaxed) ops: bypass L1/L2, no cache maintenance.
__device__ __forceinline__ u64 ald(const u64* p) {
    return __hip_atomic_load(p, __ATOMIC_RELAXED, __HIP_MEMORY_SCOPE_AGENT);
}
__device__ __forceinline__ void ast(uint* p, uint v) {
    __hip_atomic_store(p, v, __ATOMIC_RELAXED, __HIP_MEMORY_SCOPE_AGENT);
}
__device__ __forceinline__ void astq(u64* p, u64 v) {
    __hip_atomic_store(p, v, __ATOMIC_RELAXED, __HIP_MEMORY_SCOPE_AGENT);
}
__device__ __forceinline__ bf16x8 mk(u64 lo, u64 hi) {
    union { u64 q[2]; bf16x8 v; } u; u.q[0] = lo; u.q[1] = hi; return u.v;
}

// swizzle for out_gemm's B tile only
__device__ __forceinline__ int swzE(int row, int k) {
    return row * 512 + (k ^ ((row & 7) << 3));
}

// ==========================================================================
// FAST kernel: full-T h buffers (fresh addresses) -> consumers use NORMAL
// cached loads (per-XCD L2 deduplicates the 64x h-tile broadcast); producers
// store h direct-to-LLC (8B packed); flags on the bypass path; one-time
// acquire (L1/L2 inv) at kernel start clears stale/poison lines.
// ==========================================================================

__global__ __launch_bounds__(THREADS, 1)
void lstm_scan_fast(const float* __restrict__ feat,
                    const float* __restrict__ wih0, const float* __restrict__ whh0,
                    const float* __restrict__ bih0, const float* __restrict__ bhh0,
                    const float* __restrict__ wih1, const float* __restrict__ whh1,
                    const float* __restrict__ bih1, const float* __restrict__ bhh1,
                    const float* __restrict__ wih2, const float* __restrict__ whh2,
                    const float* __restrict__ bih2, const float* __restrict__ bhh2,
                    ushort* h0buf, ushort* h1buf, ushort* h2buf,
                    uint* flags) {
    const int blk = blockIdx.x, L = blk >> 6, wg = blk & 63;
    const int tid = threadIdx.x, wv = tid >> 6, l = tid & 63;
    const int c16 = l & 15, hi8 = c16 >> 3, jl = c16 & 7, kq = l >> 4;
    const int krow = kq * 8;
    const int rowbase = wv * 16;
    const int arow = rowbase + c16;

    // one-time L1+L2 invalidate (acquire at agent scope) BEFORE any reads.
    (void)__hip_atomic_load(flags, __ATOMIC_ACQUIRE, __HIP_MEMORY_SCOPE_AGENT);
    __syncthreads();

    const float* wih_g = (L == 0) ? wih0 : (L == 1) ? wih1 : wih2;
    const float* whh_g = (L == 0) ? whh0 : (L == 1) ? whh1 : whh2;
    const float* bih_g = (L == 0) ? bih0 : (L == 1) ? bih1 : bih2;
    const float* bhh_g = (L == 0) ? bhh0 : (L == 1) ? bhh1 : bhh2;
    const ushort* xsrc = (L == 1) ? h0buf : (L == 2) ? h1buf : nullptr;
    ushort* hout = (L == 0) ? h0buf : (L == 1) ? h1buf : h2buf;

    const int gcol0 = hi8 * 512 + wg * 8 + jl;
    const int gcol1 = (2 + hi8) * 512 + wg * 8 + jl;

    bf16x8 whhF[16][2];
    #pragma unroll
    for (int ks = 0; ks < 16; ++ks) {
        whhF[ks][0] = packW(whh_g + (size_t)gcol0 * 512 + ks * 32 + krow);
        whhF[ks][1] = packW(whh_g + (size_t)gcol1 * 512 + ks * 32 + krow);
    }
    bf16x8 wihF[16][2];
    if (L > 0) {
        #pragma unroll
        for (int ks = 0; ks < 16; ++ks) {
            wihF[ks][0] = packW(wih_g + (size_t)gcol0 * 512 + ks * 32 + krow);
            wihF[ks][1] = packW(wih_g + (size_t)gcol1 * 512 + ks * 32 + krow);
        }
    }
    const float bias0 = bih_g[gcol0] + bhh_g[gcol0];
    const float bias1 = bih_g[gcol1] + bhh_g[gcol1];
    float w0a[6], w0b[6];
    if (L == 0) {
        #pragma unroll
        for (int d = 0; d < 6; ++d) {
            w0a[d] = wih0[gcol0 * 6 + d];
            w0b[d] = wih0[gcol1 * 6 + d];
        }
    }
    f32x4 cstv = {0.f, 0.f, 0.f, 0.f};

    for (int t = 0; t < T_STEPS; ++t) {
        float xv[4][6];
        if (L == 0) {
            #pragma unroll
            for (int r = 0; r < 4; ++r)
                #pragma unroll
                for (int d = 0; d < 6; ++d)
                    xv[r][d] = feat[(size_t)((rowbase + kq * 4 + r) * 6 + d) * T_STEPS + t];
        }

        // decoupled flow-control poll: L waits for L-1 >= t+1 (x ready) and
        // own layer >= t (h[t-1] ready). No backpressure (full-T buffers).
        {
            int thr = NEG_INF;
            if (tid < NWG) {
                int g = tid >> 6;
                if (L == 0)      thr = (g == 0) ? t : NEG_INF;
                else if (L == 1) thr = (g == 0) ? t + 1 : (g == 1) ? t : NEG_INF;
                else             thr = (g == 1) ? t + 1 : (g == 2) ? t : NEG_INF;
            }
            for (;;) {
                int ok = 1;
                if (thr > 0)
                    ok = ((int)__hip_atomic_load(flags + tid * 32, __ATOMIC_RELAXED,
                                                 __HIP_MEMORY_SCOPE_AGENT) >= thr);
                if (__syncthreads_and(ok)) break;
                __builtin_amdgcn_s_sleep(2);
            }
        }

        {
            f32x4 acc0 = {0.f, 0.f, 0.f, 0.f};
            f32x4 acc1 = {0.f, 0.f, 0.f, 0.f};

            if (L > 0) {
                const ushort* xp = xsrc + (size_t)t * HSTRIDE + arow * 512 + krow;
                if (t > 0) {
                    const ushort* hp = hout + (size_t)(t - 1) * HSTRIDE + arow * 512 + krow;
                    f32x4 e0 = {0.f, 0.f, 0.f, 0.f}, e1 = {0.f, 0.f, 0.f, 0.f};
                    #pragma unroll
                    for (int ks = 0; ks < 16; ++ks) {
                        bf16x8 ax = *(const bf16x8*)(xp + ks * 32);  // cached
                        bf16x8 ah = *(const bf16x8*)(hp + ks * 32);  // cached
                        acc0 = __builtin_amdgcn_mfma_f32_16x16x32_bf16(ax, wihF[ks][0], acc0, 0, 0, 0);
                        acc1 = __builtin_amdgcn_mfma_f32_16x16x32_bf16(ax, wihF[ks][1], acc1, 0, 0, 0);
                        e0   = __builtin_amdgcn_mfma_f32_16x16x32_bf16(ah, whhF[ks][0], e0, 0, 0, 0);
                        e1   = __builtin_amdgcn_mfma_f32_16x16x32_bf16(ah, whhF[ks][1], e1, 0, 0, 0);
                    }
                    acc0 += e0; acc1 += e1;
                } else {
                    #pragma unroll
                    for (int ks = 0; ks < 16; ++ks) {
                        bf16x8 ax = *(const bf16x8*)(xp + ks * 32);
                        acc0 = __builtin_amdgcn_mfma_f32_16x16x32_bf16(ax, wihF[ks][0], acc0, 0, 0, 0);
                        acc1 = __builtin_amdgcn_mfma_f32_16x16x32_bf16(ax, wihF[ks][1], acc1, 0, 0, 0);
                    }
                }
            } else if (t > 0) {
                const ushort* hp = h0buf + (size_t)(t - 1) * HSTRIDE + arow * 512 + krow;
                #pragma unroll
                for (int ks = 0; ks < 16; ++ks) {
                    bf16x8 ah = *(const bf16x8*)(hp + ks * 32);
                    acc0 = __builtin_amdgcn_mfma_f32_16x16x32_bf16(ah, whhF[ks][0], acc0, 0, 0, 0);
                    acc1 = __builtin_amdgcn_mfma_f32_16x16x32_bf16(ah, whhF[ks][1], acc1, 0, 0, 0);
                }
            }

            #pragma unroll
            for (int r = 0; r < 4; ++r) { acc0[r] += bias0; acc1[r] += bias1; }
            if (L == 0) {
                #pragma unroll
                for (int r = 0; r < 4; ++r) {
                    float s0 = 0.f, s1 = 0.f;
                    #pragma unroll
                    for (int d = 0; d < 6; ++d) {
                        s0 += w0a[d] * xv[r][d];
                        s1 += w0b[d] * xv[r][d];
                    }
                    acc0[r] += s0; acc1[r] += s1;
                }
            }

            // gates -> h; pack 4 h values (8B) per LLC store via xor1 + xor2.
            ushort* hdst = hout + (size_t)t * HSTRIDE;
            #pragma unroll
            for (int r = 0; r < 4; ++r) {
                float fo0 = __shfl_xor(acc0[r], 8, 64);
                float fo1 = __shfl_xor(acc1[r], 8, 64);
                uint hv = 0;
                if (hi8 == 0) {
                    float ii = sigm(acc0[r]), gg = tanh_(acc1[r]);
                    float ff = sigm(fo0),    oo = sigm(fo1);
                    float c = ff * cstv[r] + ii * gg;
                    cstv[r] = c;
                    hv = (uint)f2bf(oo * tanh_(c));
                }
                uint w1 = __shfl_xor(hv, 1, 64);
                uint word = hv | (w1 << 16);         // valid at even jl
                uint w2 = __shfl_xor(word, 2, 64);
                if (hi8 == 0 && !(jl & 3)) {
                    u64 q = (u64)word | ((u64)w2 << 32);   // j..j+3
                    int b = rowbase + kq * 4 + r;
                    int j = wg * 8 + jl;
                    astq((u64*)&hdst[b * 512 + j], q);
                }
            }
        }

        __syncthreads();   // per-wave vmcnt(0) drains LLC stores
        if (tid == 0)
            ast(flags + blk * 32, (uint)(t + 1));
    }
}

// ==========================================================================
// FALLBACK kernel: proven round-9 ring version (bypass loads, small ws).
// ==========================================================================

__global__ __launch_bounds__(THREADS, 1)
void lstm_scan_ring(const float* __restrict__ feat,
                    const float* __restrict__ wih0, const float* __restrict__ whh0,
                    const float* __restrict__ bih0, const float* __restrict__ bhh0,
                    const float* __restrict__ wih1, const float* __restrict__ whh1,
                    const float* __restrict__ bih1, const float* __restrict__ bhh1,
                    const float* __restrict__ wih2, const float* __restrict__ whh2,
                    const float* __restrict__ bih2, const float* __restrict__ bhh2,
                    ushort* h0buf, ushort* h1buf, ushort* h2ring, ushort* ybuf,
                    uint* flags) {
    const int blk = blockIdx.x, L = blk >> 6, wg = blk & 63;
    const int tid = threadIdx.x, wv = tid >> 6, l = tid & 63;
    const int c16 = l & 15, hi8 = c16 >> 3, jl = c16 & 7, kq = l >> 4;
    const int krow = kq * 8;
    const int rowbase = wv * 16;
    const int arow = rowbase + c16;

    const float* wih_g = (L == 0) ? wih0 : (L == 1) ? wih1 : wih2;
    const float* whh_g = (L == 0) ? whh0 : (L == 1) ? whh1 : whh2;
    const float* bih_g = (L == 0) ? bih0 : (L == 1) ? bih1 : bih2;
    const float* bhh_g = (L == 0) ? bhh0 : (L == 1) ? bhh1 : bhh2;
    const ushort* xsrc = (L == 1) ? h0buf : (L == 2) ? h1buf : nullptr;
    ushort* hout = (L == 0) ? h0buf : (L == 1) ? h1buf : nullptr;

    const int gcol0 = hi8 * 512 + wg * 8 + jl;
    const int gcol1 = (2 + hi8) * 512 + wg * 8 + jl;

    bf16x8 whhF[16][2];
    #pragma unroll
    for (int ks = 0; ks < 16; ++ks) {
        whhF[ks][0] = packW(whh_g + (size_t)gcol0 * 512 + ks * 32 + krow);
        whhF[ks][1] = packW(whh_g + (size_t)gcol1 * 512 + ks * 32 + krow);
    }
    bf16x8 wihF[16][2];
    if (L > 0) {
        #pragma unroll
        for (int ks = 0; ks < 16; ++ks) {
            wihF[ks][0] = packW(wih_g + (size_t)gcol0 * 512 + ks * 32 + krow);
            wihF[ks][1] = packW(wih_g + (size_t)gcol1 * 512 + ks * 32 + krow);
        }
    }
    const float bias0 = bih_g[gcol0] + bhh_g[gcol0];
    const float bias1 = bih_g[gcol1] + bhh_g[gcol1];
    float w0a[6], w0b[6];
    if (L == 0) {
        #pragma unroll
        for (int d = 0; d < 6; ++d) {
            w0a[d] = wih0[gcol0 * 6 + d];
            w0b[d] = wih0[gcol1 * 6 + d];
        }
    }
    f32x4 cstv = {0.f, 0.f, 0.f, 0.f};

    for (int t = 0; t < T_STEPS; ++t) {
        float xv[4][6];
        if (L == 0) {
            #pragma unroll
            for (int r = 0; r < 4; ++r)
                #pragma unroll
                for (int d = 0; d < 6; ++d)
                    xv[r][d] = feat[(size_t)((rowbase + kq * 4 + r) * 6 + d) * T_STEPS + t];
        }

        {
            int thr = NEG_INF;
            if (tid < NWG) {
                int g = tid >> 6;
                if (L == 0)      thr = (g == 0) ? t     : (g == 1) ? t - 3 : NEG_INF;
                else if (L == 1) thr = (g == 0) ? t + 1 : (g == 1) ? t     : t - 3;
                else             thr = (g == 1) ? t + 1 : (g == 2) ? t     : NEG_INF;
            }
            for (;;) {
                int ok = 1;
                if (thr > 0)
                    ok = ((int)__hip_atomic_load(flags + tid * 32, __ATOMIC_RELAXED,
                                                 __HIP_MEMORY_SCOPE_AGENT) >= thr);
                if (__syncthreads_and(ok)) break;
                __builtin_amdgcn_s_sleep(4);
            }
        }

        {
            f32x4 acc0 = {0.f, 0.f, 0.f, 0.f};
            f32x4 acc1 = {0.f, 0.f, 0.f, 0.f};

            if (L > 0) {
                const u64* xp = (const u64*)(xsrc + (size_t)(t & (RING - 1)) * HSLICE
                                             + arow * 512 + krow);
                if (t > 0) {
                    const ushort* hsrc = (L == 2)
                        ? h2ring + (size_t)((t - 1) & 1) * HSLICE
                        : hout + (size_t)((t - 1) & (RING - 1)) * HSLICE;
                    const u64* hp = (const u64*)(hsrc + arow * 512 + krow);
                    f32x4 e0 = {0.f, 0.f, 0.f, 0.f}, e1 = {0.f, 0.f, 0.f, 0.f};
                    #pragma unroll
                    for (int ks = 0; ks < 16; ++ks) {
                        bf16x8 ax = mk(ald(xp + ks * 8), ald(xp + ks * 8 + 1));
                        bf16x8 ah = mk(ald(hp + ks * 8), ald(hp + ks * 8 + 1));
                        acc0 = __builtin_amdgcn_mfma_f32_16x16x32_bf16(ax, wihF[ks][0], acc0, 0, 0, 0);
                        acc1 = __builtin_amdgcn_mfma_f32_16x16x32_bf16(ax, wihF[ks][1], acc1, 0, 0, 0);
                        e0   = __builtin_amdgcn_mfma_f32_16x16x32_bf16(ah, whhF[ks][0], e0, 0, 0, 0);
                        e1   = __builtin_amdgcn_mfma_f32_16x16x32_bf16(ah, whhF[ks][1], e1, 0, 0, 0);
                    }
                    acc0 += e0; acc1 += e1;
                } else {
                    #pragma unroll
                    for (int ks = 0; ks < 16; ++ks) {
                        bf16x8 ax = mk(ald(xp + ks * 8), ald(xp + ks * 8 + 1));
                        acc0 = __builtin_amdgcn_mfma_f32_16x16x32_bf16(ax, wihF[ks][0], acc0, 0, 0, 0);
                        acc1 = __builtin_amdgcn_mfma_f32_16x16x32_bf16(ax, wihF[ks][1], acc1, 0, 0, 0);
                    }
                }
            } else if (t > 0) {
                const u64* hp = (const u64*)(h0buf + (size_t)((t - 1) & (RING - 1)) * HSLICE
                                             + arow * 512 + krow);
                #pragma unroll
                for (int ks = 0; ks < 16; ++ks) {
                    bf16x8 ah = mk(ald(hp + ks * 8), ald(hp + ks * 8 + 1));
                    acc0 = __builtin_amdgcn_mfma_f32_16x16x32_bf16(ah, whhF[ks][0], acc0, 0, 0, 0);
                    acc1 = __builtin_amdgcn_mfma_f32_16x16x32_bf16(ah, whhF[ks][1], acc1, 0, 0, 0);
                }
            }

            #pragma unroll
            for (int r = 0; r < 4; ++r) { acc0[r] += bias0; acc1[r] += bias1; }
            if (L == 0) {
                #pragma unroll
                for (int r = 0; r < 4; ++r) {
                    float s0 = 0.f, s1 = 0.f;
                    #pragma unroll
                    for (int d = 0; d < 6; ++d) {
                        s0 += w0a[d] * xv[r][d];
                        s1 += w0b[d] * xv[r][d];
                    }
                    acc0[r] += s0; acc1[r] += s1;
                }
            }

            #pragma unroll
            for (int r = 0; r < 4; ++r) {
                float fo0 = __shfl_xor(acc0[r], 8, 64);
                float fo1 = __shfl_xor(acc1[r], 8, 64);
                uint hv = 0;
                if (hi8 == 0) {
                    float ii = sigm(acc0[r]), gg = tanh_(acc1[r]);
                    float ff = sigm(fo0),    oo = sigm(fo1);
                    float c = ff * cstv[r] + ii * gg;
                    cstv[r] = c;
                    hv = (uint)f2bf(oo * tanh_(c));
                }
                uint other = __shfl_xor(hv, 1, 64);
                if (hi8 == 0 && !(jl & 1)) {
                    uint word = hv | (other << 16);
                    int b = rowbase + kq * 4 + r;
                    int j = wg * 8 + jl;
                    if (L == 2) {
                        ast((uint*)&h2ring[(size_t)(t & 1) * HSLICE + b * 512 + j], word);
                        if ((t & 7) == 7)
                            *(uint*)&ybuf[(size_t)(t >> 3) * HSLICE + b * 512 + j] = word;
                    } else {
                        ast((uint*)&hout[(size_t)(t & (RING - 1)) * HSLICE + b * 512 + j], word);
                    }
                }
            }
        }

        __syncthreads();
        if (tid == 0)
            ast(flags + blk * 32, (uint)(t + 1));
    }
}

// ---- final projection: out[8192][256] = y @ w_out^T + b_out --------------
// A-tile bm (64 rows) is read at y + base_off + bm*tile_stride.

__global__ __launch_bounds__(256, 1)
void out_gemm(const ushort* __restrict__ y, size_t base_off, size_t tile_stride,
              const float* __restrict__ wout, const float* __restrict__ bout,
              float* __restrict__ out, const uint* __restrict__ sync_dummy) {
    (void)__hip_atomic_load(sync_dummy, __ATOMIC_ACQUIRE, __HIP_MEMORY_SCOPE_AGENT);
    __shared__ ushort Bl[64 * 512];
    const int bm = blockIdx.x;
    const int bn = blockIdx.y;
    const int tid = threadIdx.x, wv = tid >> 6, l = tid & 63;

    #pragma unroll
    for (int i = 0; i < 16; ++i) {
        int c = tid + 256 * i;
        int n = c >> 6;
        int kE = (c & 63) << 3;
        const float* s = wout + (size_t)(bn * 64 + n) * 512 + kE;
        float4 f0 = *(const float4*)s;
        float4 f1 = *(const float4*)(s + 4);
        uint4 v;
        v.x = (uint)f2bf(f0.x) | ((uint)f2bf(f0.y) << 16);
        v.y = (uint)f2bf(f0.z) | ((uint)f2bf(f0.w) << 16);
        v.z = (uint)f2bf(f1.x) | ((uint)f2bf(f1.y) << 16);
        v.w = (uint)f2bf(f1.z) | ((uint)f2bf(f1.w) << 16);
        *(uint4*)(Bl + swzE(n, kE)) = v;
    }
    __syncthreads();

    const ushort* atile = y + base_off + (size_t)bm * tile_stride;
    const int arow = (wv << 4) + (l & 15);
    const int koff = (l >> 4) << 3;
    f32x4 acc[4] = {{0.f,0.f,0.f,0.f},{0.f,0.f,0.f,0.f},{0.f,0.f,0.f,0.f},{0.f,0.f,0.f,0.f}};
    for (int ks = 0; ks < 16; ++ks) {
        int k = (ks << 5) + koff;
        bf16x8 a = *(const bf16x8*)(atile + (size_t)arow * 512 + k);
        #pragma unroll
        for (int nt = 0; nt < 4; ++nt) {
            bf16x8 b = *(const bf16x8*)(Bl + swzE((nt << 4) + (l & 15), k));
            acc[nt] = __builtin_amdgcn_mfma_f32_16x16x32_bf16(a, b, acc[nt], 0, 0, 0);
        }
    }
    const int m0 = bm * 64 + (wv << 4);
    const int r0 = (l >> 4) << 2;
    #pragma unroll
    for (int nt = 0; nt < 4; ++nt) {
        int n = bn * 64 + (nt << 4) + (l & 15);
        float bo = bout[n];
        #pragma unroll
        for (int r = 0; r < 4; ++r) {
            int m = m0 + r0 + r;
            out[(size_t)m * 256 + n] = acc[nt][r] + bo;
        }
    }
}

// ---- launch --------------------------------------------------------------

extern "C" void kernel_launch(void* const* d_in, const int* in_sizes, int n_in,
                              void* d_out, int out_size, void* d_ws, size_t ws_size,
                              hipStream_t stream) {
    const float* feat = (const float*)d_in[0];
    const float* wih0 = (const float*)d_in[1];
    const float* whh0 = (const float*)d_in[2];
    const float* bih0 = (const float*)d_in[3];
    const float* bhh0 = (const float*)d_in[4];
    const float* wih1 = (const float*)d_in[5];
    const float* whh1 = (const float*)d_in[6];
    const float* bih1 = (const float*)d_in[7];
    const float* bhh1 = (const float*)d_in[8];
    const float* wih2 = (const float*)d_in[9];
    const float* whh2 = (const float*)d_in[10];
    const float* bih2 = (const float*)d_in[11];
    const float* bhh2 = (const float*)d_in[12];
    const float* wout = (const float*)d_in[13];
    const float* bout = (const float*)d_in[14];
    float* out = (float*)d_out;

    char* ws = (char*)d_ws;
    uint* flags = (uint*)ws;
    (void)hipMemsetAsync(flags, 0, 32768, stream);

    const size_t hbytes = (size_t)T_STEPS * HSTRIDE * 2;   // ~67.2 MB
    const size_t fast_need = 32768 + 3 * hbytes;

    if (ws_size >= fast_need) {
        ushort* h0 = (ushort*)(ws + 32768);
        ushort* h1 = (ushort*)((char*)h0 + hbytes);
        ushort* h2 = (ushort*)((char*)h1 + hbytes);
        hipLaunchKernelGGL(lstm_scan_fast, dim3(NWG), dim3(THREADS), 0, stream,
                           feat, wih0, whh0, bih0, bhh0, wih1, whh1, bih1, bhh1,
                           wih2, whh2, bih2, bhh2, h0, h1, h2, flags);
        hipLaunchKernelGGL(out_gemm, dim3(128, 4), dim3(256), 0, stream,
                           h2, (size_t)7 * HSTRIDE, (size_t)8 * HSTRIDE,
                           wout, bout, out, flags);
    } else {
        ushort* h0   = (ushort*)(ws + 32768);
        ushort* h1   = h0 + (size_t)RING * HSLICE;
        ushort* h2r  = h1 + (size_t)RING * HSLICE;
        ushort* ybuf = h2r + (size_t)2 * HSLICE;
        hipLaunchKernelGGL(lstm_scan_ring, dim3(NWG), dim3(THREADS), 0, stream,
                           feat, wih0, whh0, bih0, bhh0, wih1, whh1, bih1, bhh1,
                           wih2, whh2, bih2, bhh2, h0, h1, h2r, ybuf, flags);
        hipLaunchKernelGGL(out_gemm, dim3(128, 4), dim3(256), 0, stream,
                           ybuf, (size_t)0, (size_t)HSLICE,
                           wout, bout, out, flags);
    }
}